// Round 4
// baseline (176.302 us; speedup 1.0000x reference)
//
#include <hip/hip_runtime.h>

// Flatten 2x2 blocks, fp32 in/out:
//   out[b, c*H*W + i*2W + 4*j + 2*r + s] = x[b, c, 2i+r, 2j+s]
// (i in [0,H/2), j in [0,W/2), r,s in {0,1}; per-plane i-stride is
//  W/2*4 = 2W = 1024 — NOT W; this was round 0's bug.)
//
// Each thread handles (bc, i, tj), tj indexing groups of 4 input columns:
//   load  float4 r0 = x[bc, 2i,   4tj..4tj+3]
//   load  float4 r1 = x[bc, 2i+1, 4tj..4tj+3]
//   store {r0.x,r0.y,r1.x,r1.y} at out[plane + i*1024 + 8tj]     (j = 2tj)
//   store {r0.z,r0.w,r1.z,r1.w} at out[plane + i*1024 + 8tj + 4] (j = 2tj+1)
// All addresses 16B-aligned; loads and stores fully coalesced.

namespace {
constexpr int B = 32;
constexpr int C = 3;
constexpr int H = 512;
constexpr int W = 512;
constexpr int HALF_H = H / 2;      // 256
constexpr int QW = W / 4;          // 128 (thread handles 4 input cols)
constexpr long long TOTAL_THREADS = (long long)B * C * HALF_H * QW;  // 3,145,728
}

__global__ __launch_bounds__(256) void flatten2x2_kernel(const float* __restrict__ x,
                                                         float* __restrict__ out) {
    long long t = (long long)blockIdx.x * blockDim.x + threadIdx.x;
    if (t >= TOTAL_THREADS) return;

    int tj = (int)(t % QW);
    long long rest = t / QW;
    int i = (int)(rest % HALF_H);
    int bc = (int)(rest / HALF_H);   // fused b*C + c index

    long long plane = (long long)bc * H * W;
    const float4* row0 = (const float4*)(x + plane + (long long)(2 * i) * W);
    const float4* row1 = (const float4*)(x + plane + (long long)(2 * i + 1) * W);

    float4 r0 = row0[tj];
    float4 r1 = row1[tj];

    // Output super-row stride is 2W = 1024 floats.
    float4* o = (float4*)(out + plane + (long long)i * (2 * W) + (long long)8 * tj);
    o[0] = make_float4(r0.x, r0.y, r1.x, r1.y);
    o[1] = make_float4(r0.z, r0.w, r1.z, r1.w);
}

extern "C" void kernel_launch(void* const* d_in, const int* in_sizes, int n_in,
                              void* d_out, int out_size, void* d_ws, size_t ws_size,
                              hipStream_t stream) {
    const float* x = (const float*)d_in[0];
    float* out = (float*)d_out;

    const int block = 256;
    const int grid = (int)((TOTAL_THREADS + block - 1) / block);  // 12288
    flatten2x2_kernel<<<grid, block, 0, stream>>>(x, out);
}

// Round 5
// 172.975 us; speedup vs baseline: 1.0192x; 1.0192x over previous
//
#include <hip/hip_runtime.h>

// Flatten 2x2 blocks, fp32:
//   out[plane + i*1024 + 4j + 2r + s] = x[plane + (2i+r)*512 + 2j + s]
// Pure permutation, memory-bound (201 MB total). Round-4 version passed at
// 59 us (~3.4 TB/s) with half-density stores (16B/lane @ 32B stride).
// This version stages 16KB tiles through LDS so BOTH global sides are dense
// 16B/lane coalesced.
//
// Tile = 4096 floats = 8 input rows = 4 output superrows. Key identity:
// output superrow i occupies plane floats [i*1024, i*1024+1024) and is built
// from input rows 2i,2i+1 = plane floats [i*1024, i*1024+1024) — the SAME
// range, so each 16KB tile is a self-contained permutation and planes
// (262144 floats) split into exactly 64 tiles.
//
// Per block (256 thr = 4 waves), wave w owns tile quarter [1024w, 1024w+1024):
//   stage: 4x dwordx4 global loads (dense) -> LDS (ds_write_b128, dense)
//   emit:  out f4 #j = {row0.f2[j], row1.f2[j]} via 2x ds_read_b64 (stride
//          8B, conflict-free) -> 4x dwordx4 global stores (dense).

namespace {
constexpr int B = 32;
constexpr int C = 3;
constexpr int H = 512;
constexpr int W = 512;
constexpr int TILE_FLOATS = 4096;                                // 16 KB
constexpr int NTILES = B * C * H * W / TILE_FLOATS;              // 6144
}

__global__ __launch_bounds__(256) void flatten2x2_lds(const float* __restrict__ x,
                                                      float* __restrict__ out) {
    __shared__ float lds[TILE_FLOATS];

    const int tid = threadIdx.x;
    const int w = tid >> 6;        // wave id 0..3
    const int lane = tid & 63;

    const long long tile = (long long)blockIdx.x * TILE_FLOATS;

    // --- stage: wave w copies tile floats [1024w, 1024w+1024) into LDS ---
    const float4* __restrict__ src = (const float4*)(x + tile + 1024 * w);
    float4* ldsv = (float4*)(lds + 1024 * w);
#pragma unroll
    for (int m = 0; m < 4; ++m) {
        ldsv[64 * m + lane] = src[64 * m + lane];
    }
    __syncthreads();

    // --- emit: output superrow (tile-local w): 256 dense float4s ---
    const float2* r0 = (const float2*)(lds + 1024 * w);        // input row 2i
    const float2* r1 = (const float2*)(lds + 1024 * w + 512);  // input row 2i+1
    float4* __restrict__ dst = (float4*)(out + tile + 1024 * w);
#pragma unroll
    for (int m = 0; m < 4; ++m) {
        const int j = 64 * m + lane;
        const float2 a = r0[j];
        const float2 b = r1[j];
        dst[j] = make_float4(a.x, a.y, b.x, b.y);
    }
}

extern "C" void kernel_launch(void* const* d_in, const int* in_sizes, int n_in,
                              void* d_out, int out_size, void* d_ws, size_t ws_size,
                              hipStream_t stream) {
    const float* x = (const float*)d_in[0];
    float* out = (float*)d_out;

    flatten2x2_lds<<<NTILES, 256, 0, stream>>>(x, out);
}